// Round 17
// baseline (2131.887 us; speedup 1.0000x reference)
//
#include <hip/hip_runtime.h>
#include <stdint.h>

#define BB 4
#define NN 8192
#define SS 2048
#define KK 16
#define IND 64
#define CIN 67
#define OD 128

typedef unsigned int   u32;
typedef unsigned long long u64;
typedef float f2 __attribute__((ext_vector_type(2)));

#define TAG 0x5EED0000u
#define CW  252                      // consumer blocks
#define GRID (BB + CW)               // 256 blocks, 1/CU -> all co-resident
#define NWAVES (CW*8)                // 2016 consumer waves
#define SLICE 3632                   // floats per consumer wave slice (gbuf 1072 + hbuf 2560)
#define DYN_LDS (8*SLICE*4)          // 116224 B >= FPS's 98304 B coord need

// LDS-only barrier: drains lgkmcnt (DS ops) but lets global stores ride across.
// __syncthreads would emit s_waitcnt vmcnt(0) before s_barrier (m97), stalling the
// storing wave ~300-500cyc at every chunk-store iteration. The loop barrier only
// protects LDS (pkey), so lgkmcnt(0) suffices; cross-XCD visibility of the chunk
// stores is provided by the periodic RELEASE publish (Guideline 16).
#define LDS_BARRIER() asm volatile("s_waitcnt lgkmcnt(0)\n\ts_barrier" ::: "memory")

template<int CTRL>
__device__ __forceinline__ float dpp_mv(float x){
  int xi = __builtin_bit_cast(int, x);
  int r  = __builtin_amdgcn_update_dpp(xi, xi, CTRL, 0xf, 0xf, false);
  return __builtin_bit_cast(float, r);
}

// ---------------- fused: blocks 0..3 = FPS producer; blocks 4..255 = knn+mlp consumers --
#define FPT 512
#define PPT (NN/FPT)   // 16
#define NW  (FPT/64)   // 8
__global__ __launch_bounds__(512) void k_fused(const float* __restrict__ xyz,
                                               float* __restrict__ out_xyz,
                                               const float* __restrict__ feat,
                                               const float* __restrict__ W1, const float* __restrict__ b1,
                                               const float* __restrict__ W2, const float* __restrict__ b2,
                                               const float* __restrict__ g_ln, const float* __restrict__ b_ln,
                                               float* __restrict__ out_feat,
                                               u32* __restrict__ progress){
  extern __shared__ float smem[];
  __shared__ u64 pkey[2][NW];
  __shared__ float ring[16*3];               // producer center ring (chunked store)
  int tid = threadIdx.x;
  int wid = tid >> 6, lane = tid & 63;

  if (blockIdx.x < BB){
    // =========================== FPS producer ==========================================
    #pragma clang fp contract(off)
    float* sx = smem;                 // [NN]
    float* sy = smem +   NN;          // [NN]
    float* sz = smem + 2*NN;          // [NN]
    int b = blockIdx.x;
    const float4* Xv = (const float4*)(xyz + (size_t)b*NN*3);  // 192B/thread, 16B aligned
    float f[48];
    #pragma unroll
    for (int v=0;v<12;v++){
      float4 t4 = Xv[tid*12 + v];
      f[4*v+0]=t4.x; f[4*v+1]=t4.y; f[4*v+2]=t4.z; f[4*v+3]=t4.w;
    }
    f2 X[PPT/2], Y[PPT/2], Z[PPT/2], D[PPT/2];
    #pragma unroll
    for (int jp=0;jp<PPT/2;jp++){
      int j0 = 2*jp, j1 = 2*jp+1;
      X[jp] = (f2){f[3*j0+0], f[3*j1+0]};
      Y[jp] = (f2){f[3*j0+1], f[3*j1+1]};
      Z[jp] = (f2){f[3*j0+2], f[3*j1+2]};
      D[jp] = (f2){1e10f, 1e10f};
      int n0 = tid*PPT + j0;
      sx[n0]=f[3*j0+0]; sx[n0+1]=f[3*j1+0];
      sy[n0]=f[3*j0+1]; sy[n0+1]=f[3*j1+1];
      sz[n0]=f[3*j0+2]; sz[n0+1]=f[3*j1+2];
    }
    const float* X0 = xyz + (size_t)b*NN*3;
    float cx=X0[0], cy=X0[1], cz=X0[2];      // uniform (scalar) loads
    size_t ob = (size_t)b*SS*3;
    if (tid==1){
      out_xyz[ob+0]=cx; out_xyz[ob+1]=cy; out_xyz[ob+2]=cz;
      ring[0]=cx; ring[1]=cy; ring[2]=cz;
      __hip_atomic_store(&progress[b], TAG|0u, __ATOMIC_RELEASE, __HIP_MEMORY_SCOPE_AGENT);
    }
    __syncthreads();                         // once: full fence after staging

    for (int it=1; it<SS; ++it){
      f2 mm0 = (f2){-1.0f, -1.0f}, mm1 = (f2){-1.0f, -1.0f};
      #pragma unroll
      for (int jp=0;jp<PPT/2;jp+=2){
        f2 dx0 = X[jp] - cx,   dy0 = Y[jp] - cy,   dz0 = Z[jp] - cz;
        f2 dx1 = X[jp+1] - cx, dy1 = Y[jp+1] - cy, dz1 = Z[jp+1] - cz;
        f2 d0  = ((dx0*dx0) + (dy0*dy0)) + (dz0*dz0);   // ((dx2+dy2)+dz2), numpy rn order
        f2 d1  = ((dx1*dx1) + (dy1*dy1)) + (dz1*dz1);
        f2 nd0 = __builtin_elementwise_min(D[jp],   d0);
        f2 nd1 = __builtin_elementwise_min(D[jp+1], d1);
        D[jp]   = nd0;
        D[jp+1] = nd1;
        mm0 = __builtin_elementwise_max(mm0, nd0);
        mm1 = __builtin_elementwise_max(mm1, nd1);
      }
      f2 mm = __builtin_elementwise_max(mm0, mm1);
      float md = fmaxf(mm.x, mm.y);
      float m = md;
      m = fmaxf(m, dpp_mv<0x111>(m));
      m = fmaxf(m, dpp_mv<0x112>(m));
      m = fmaxf(m, dpp_mv<0x114>(m));
      m = fmaxf(m, dpp_mv<0x118>(m));
      m = fmaxf(m, dpp_mv<0x142>(m));
      m = fmaxf(m, dpp_mv<0x143>(m));
      float wmax = __builtin_bit_cast(float,
          __builtin_amdgcn_readlane(__builtin_bit_cast(int, m), 63));
      u64 ball = __ballot(md == wmax);
      int wl = __ffsll((unsigned long long)ball) - 1;
      if (lane == wl){
        int bj = 0;
        #pragma unroll
        for (int t=PPT-1;t>=0;--t){
          float v = (t&1)? D[t>>1].y : D[t>>1].x;
          if (v == wmax) bj = t;
        }
        int widx = tid*PPT + bj;
        pkey[it&1][wid] = ((u64)__float_as_uint(wmax) << 32) | (u32)~(u32)widx;
      }
      LDS_BARRIER();                  // lgkm-only drain; chunk stores ride across
      u64 bk = pkey[it&1][0];
      #pragma unroll
      for (int w=1;w<NW;w++){
        u64 k2 = pkey[it&1][w];
        if (k2 > bk) bk = k2;
      }
      int gw = (int)~(u32)bk;
      cx = sx[gw]; cy = sy[gw]; cz = sz[gw];
      if (tid==1){                           // LDS ring write: no VMEM on critical path
        int rs = (it&15)*3;
        ring[rs]=cx; ring[rs+1]=cy; ring[rs+2]=cz;
      }
      if ((it & 15) == 15){
        if (wid==0 && lane<48){              // one coalesced 48-float chunk store (plain)
          size_t base = ob + (size_t)(it-15)*3;
          out_xyz[base + lane] = ring[lane];
        }
        // RELEASE every 128 iters: drains + writes back ALL of wave 0's outstanding
        // chunk stores, making centers up to `it` visible across XCDs (Guideline 16).
        if (tid==1 && ((it & 127) == 127)){
          __hip_atomic_store(&progress[b], TAG|(u32)it,
                             __ATOMIC_RELEASE, __HIP_MEMORY_SCOPE_AGENT);
        }
      }
    }
    return;
  }

  // ============================ consumer: knn + mlp per wave ==========================
  int gid = (blockIdx.x - BB)*8 + wid;       // 0..2015
  float* gw = smem + wid*SLICE;              // wave-private gbuf [CIN][16]
  float* hw = gw + 1072;                     // wave-private hbuf [OD][20]
  int k = lane & 15, part = lane >> 4;
  const u32* ctru = (const u32*)out_xyz;

  for (int p = gid; p < BB*SS; p += NWAVES){
    int s = p >> 2, b = p & 3;
    int q = b*SS + s;
    for(;;){
      u32 v = __hip_atomic_load(&progress[b], __ATOMIC_RELAXED, __HIP_MEMORY_SCOPE_AGENT);
      if ((v & 0xFFFF0000u) == TAG && (v & 0xFFFFu) >= (u32)s) break;
      __builtin_amdgcn_s_sleep(64);
    }
    float qx = __builtin_bit_cast(float, __hip_atomic_load(&ctru[3*q+0], __ATOMIC_RELAXED, __HIP_MEMORY_SCOPE_AGENT));
    float qy = __builtin_bit_cast(float, __hip_atomic_load(&ctru[3*q+1], __ATOMIC_RELAXED, __HIP_MEMORY_SCOPE_AGENT));
    float qz = __builtin_bit_cast(float, __hip_atomic_load(&ctru[3*q+2], __ATOMIC_RELAXED, __HIP_MEMORY_SCOPE_AGENT));
    const float* Pb = xyz + (size_t)b*NN*3;
    float q2 = __fadd_rn(__fadd_rn(__fmul_rn(qx,qx),__fmul_rn(qy,qy)),__fmul_rn(qz,qz));
    // ---- KNN: exact (q2+x2)-2dot, x2 computed inline (same rn order as reference) ---
    u64 key[KK];
    #pragma unroll
    for (int t=0;t<KK;t++) key[t] = ~0ull;
    for (int i=0;i<NN/64;i++){
      int n = i*64 + lane;
      float px = Pb[3*n], py = Pb[3*n+1], pz = Pb[3*n+2];
      float x2  = __fadd_rn(__fadd_rn(__fmul_rn(px,px),__fmul_rn(py,py)),__fmul_rn(pz,pz));
      float dot = __fadd_rn(__fadd_rn(__fmul_rn(qx,px),__fmul_rn(qy,py)),__fmul_rn(qz,pz));
      float sd  = __fsub_rn(__fadd_rn(q2,x2), __fmul_rn(2.0f,dot));
      u32 bu = __float_as_uint(sd);
      bu ^= (u32)((int)bu >> 31) | 0x80000000u;
      u64 kk = ((u64)bu<<32) | (u32)n;
      if (kk < key[KK-1]){
        key[KK-1] = kk;
        #pragma unroll
        for (int t=KK-1;t>0;--t){
          u64 a=key[t-1], c=key[t];
          bool sw = c < a;
          key[t-1] = sw? c : a;
          key[t]   = sw? a : c;
        }
      }
    }
    int n_sel = 0;
    #pragma unroll 1
    for (int r=0;r<KK;r++){
      u64 m = key[0];
      #pragma unroll
      for (int mm=1;mm<64;mm<<=1){
        u64 om = __shfl_xor((unsigned long long)m, mm, 64);
        if (om < m) m = om;
      }
      if (k == r) n_sel = (int)(u32)m;
      if (key[0]==m){
        #pragma unroll
        for (int t=0;t<KK-1;t++) key[t]=key[t+1];
        key[KK-1]=~0ull;
      }
    }
    // ---- gather into wave-private LDS (no block barrier; DS in-order per wave) ------
    {
      const float* fp = feat + ((size_t)b*NN + (size_t)n_sel)*IND + part*16;
      float4 f0 = *(const float4*)(fp+0);
      float4 f1 = *(const float4*)(fp+4);
      float4 f2v = *(const float4*)(fp+8);
      float4 f3 = *(const float4*)(fp+12);
      float v[16] = {f0.x,f0.y,f0.z,f0.w, f1.x,f1.y,f1.z,f1.w,
                     f2v.x,f2v.y,f2v.z,f2v.w, f3.x,f3.y,f3.z,f3.w};
      #pragma unroll
      for (int c=0;c<16;c++) gw[(3+part*16+c)*16 + k] = v[c];
      if (part==0){
        float ppx = Pb[3*n_sel], ppy = Pb[3*n_sel+1], ppz = Pb[3*n_sel+2];
        gw[0*16+k] = __fsub_rn(ppx, qx);
        gw[1*16+k] = __fsub_rn(ppy, qy);
        gw[2*16+k] = __fsub_rn(ppz, qz);
      }
    }
    __builtin_amdgcn_wave_barrier();
    int o = lane;
    float a0[16], a1[16];
    #pragma unroll
    for (int t=0;t<16;t++){ a0[t]=0.0f; a1[t]=0.0f; }
    #pragma unroll 4
    for (int j=0;j<CIN;j++){
      float w0 = W1[j*OD + o];
      float w1 = W1[j*OD + o + 64];
      #pragma unroll
      for (int t=0;t<16;t++){
        float gv = gw[j*16+t];
        a0[t]=fmaf(gv,w0,a0[t]); a1[t]=fmaf(gv,w1,a1[t]);
      }
    }
    float bb0 = b1[o], bb1 = b1[o+64];
    #pragma unroll
    for (int t=0;t<16;t++){
      hw[o*20+t]      = fmaxf(a0[t]+bb0, 0.0f);
      hw[(o+64)*20+t] = fmaxf(a1[t]+bb1, 0.0f);
    }
    __builtin_amdgcn_wave_barrier();
    float c0[16], c1[16];
    #pragma unroll
    for (int t=0;t<16;t++){ c0[t]=0.0f; c1[t]=0.0f; }
    #pragma unroll 4
    for (int j=0;j<OD;j++){
      float w0 = W2[j*OD + o];
      float w1 = W2[j*OD + o + 64];
      #pragma unroll
      for (int t=0;t<16;t++){
        float hv = hw[j*20+t];
        c0[t]=fmaf(hv,w0,c0[t]); c1[t]=fmaf(hv,w1,c1[t]);
      }
    }
    float m0=c0[0], m1=c1[0];
    #pragma unroll
    for (int t=1;t<16;t++){ m0=fmaxf(m0,c0[t]); m1=fmaxf(m1,c1[t]); }
    m0 += b2[o]; m1 += b2[o+64];
    float ssum = m0+m1;
    #pragma unroll
    for (int mm=1;mm<64;mm<<=1) ssum += __shfl_xor(ssum,mm,64);
    float mean = ssum * (1.0f/128.0f);
    float d0=m0-mean, d1=m1-mean;
    float sq = d0*d0 + d1*d1;
    #pragma unroll
    for (int mm=1;mm<64;mm<<=1) sq += __shfl_xor(sq,mm,64);
    float var = sq * (1.0f/128.0f);
    float x = var + 1e-5f;
    float r = rsqrtf(x);
    r = r * (1.5f - 0.5f*x*r*r);
    size_t obf = (size_t)q*OD;
    out_feat[obf+o]    = fmaf(d0*r, g_ln[o],    b_ln[o]);
    out_feat[obf+o+64] = fmaf(d1*r, g_ln[o+64], b_ln[o+64]);
  }
}

extern "C" void kernel_launch(void* const* d_in, const int* in_sizes, int n_in,
                              void* d_out, int out_size, void* d_ws, size_t ws_size,
                              hipStream_t stream){
  const float* xyz  = (const float*)d_in[0];
  const float* feat = (const float*)d_in[1];
  const float* W1   = (const float*)d_in[2];
  const float* b1   = (const float*)d_in[3];
  const float* W2   = (const float*)d_in[4];
  const float* b2   = (const float*)d_in[5];
  const float* lg   = (const float*)d_in[6];
  const float* lb   = (const float*)d_in[7];
  float* out = (float*)d_out;
  u32* progress = (u32*)d_ws;                         // 16 B, zeroed below each call
  float* out_xyz  = out;
  float* out_feat = out + (size_t)BB*SS*3;

  hipFuncSetAttribute((const void*)k_fused,
                      hipFuncAttributeMaxDynamicSharedMemorySize, DYN_LDS);

  hipMemsetAsync(progress, 0, BB*sizeof(u32), stream);  // tag!=0x5EED -> not ready
  hipLaunchKernelGGL(k_fused, dim3(GRID), dim3(512), DYN_LDS, stream,
                     xyz, out_xyz, feat, W1, b1, W2, b2, lg, lb, out_feat, progress);
}